// Round 13
// baseline (328.028 us; speedup 1.0000x reference)
//
#include <hip/hip_runtime.h>
#include <math.h>

// Problem geometry: D=256 fixed; N, K from in_sizes.
#define D      256
#define D4     64
#define TAU    6.0e-3f   // near-tie margin; bf16-3-product score error ~2e-3

// ---- MFMA-path geometry (round 10: 4-wave blocks, B via registers) ----
#define KPAD    4096     // padded subsampled-codebook size
#define NEB     128      // entry blocks of 32 (KPAD/32)
#define NSPLIT  32       // entry splits; kb = blockIdx.x & 31
#define KSPAN   128      // entries per block
#define TMTOK   128      // tokens per block
#define NSTEPK  16       // k16-groups (D/16)
#define AFRAGS  8        // per step: 4 eb x {hi,lo}  (entries staged to LDS)
#define BUFU    (AFRAGS * 512)              // ushorts per LDS buffer (8 KiB)

typedef short bf16x8 __attribute__((ext_vector_type(8)));
typedef float f32x16 __attribute__((ext_vector_type(16)));

#define GLD16(g, l) __builtin_amdgcn_global_load_lds( \
    (const __attribute__((address_space(1))) void*)(g), \
    (__attribute__((address_space(3))) void*)(l), 16, 0, 0)

__device__ inline ushort f2bf_rn(float f) {           // RNE f32 -> bf16 bits
    unsigned u = __float_as_uint(f);
    unsigned r = (u + 0x7fffu + ((u >> 16) & 1u)) >> 16;
    return (ushort)r;
}
__device__ inline float bf2f(ushort u) { return __uint_as_float(((unsigned)u) << 16); }
__device__ inline f32x16 zero16() {
    f32x16 z = {0,0,0,0,0,0,0,0,0,0,0,0,0,0,0,0};
    return z;
}
__device__ inline unsigned pack2(ushort a, ushort b) {
    return (unsigned)a | ((unsigned)b << 16);
}

// ---------------------------------------------------------------------------
// p01 v2: fragment-major pack, hi+lo fused (one read -> two plane writes).
// xpF[kg][tb][512], cpF[kg][eb][512]: kg<16 bf16hi, kg>=16 bf16lo of kg-16.
// Fragment: lane l -> row blk*32+(l&31), k'' = (l>>5)*8..+8 contiguous.
// Plus c2[k] (f64-exact, +inf pads).
__global__ __launch_bounds__(256)
void p01_pack(const float4* __restrict__ x4, const float4* __restrict__ cb4,
              const int* __restrict__ ridx, ushort* __restrict__ xpF,
              ushort* __restrict__ cpF, float* __restrict__ c2,
              int Ntok, int K) {
    const int v    = (int)(blockIdx.x * 4 + (threadIdx.x >> 6));
    const int lane = threadIdx.x & 63;
    const int l31  = lane & 31, hi = lane >> 5;
    const int NTB  = Ntok >> 5;
    const int nx   = 16 * NTB;

    if (v < nx) {                                  // ---- x fragments (hi+lo) ----
        int kg = v / NTB, tb = v - kg * NTB;
        int token = tb * 32 + l31;
        int f0 = kg * 4 + hi * 2;                  // float4 index
        float4 a = x4[(size_t)token * D4 + f0];
        float4 b = x4[(size_t)token * D4 + f0 + 1];
        float f[8] = {a.x, a.y, a.z, a.w, b.x, b.y, b.z, b.w};
        ushort uh[8], ul[8];
        #pragma unroll
        for (int i = 0; i < 8; ++i) {
            ushort hb = f2bf_rn(f[i]);
            uh[i] = hb;
            ul[i] = f2bf_rn(f[i] - bf2f(hb));
        }
        uint4 oh = {pack2(uh[0],uh[1]), pack2(uh[2],uh[3]),
                    pack2(uh[4],uh[5]), pack2(uh[6],uh[7])};
        uint4 ol = {pack2(ul[0],ul[1]), pack2(ul[2],ul[3]),
                    pack2(ul[4],ul[5]), pack2(ul[6],ul[7])};
        *(uint4*)&xpF[((size_t)kg * NTB + tb) * 512 + lane * 8]        = oh;
        *(uint4*)&xpF[((size_t)(kg + 16) * NTB + tb) * 512 + lane * 8] = ol;
        return;
    }
    int v2 = v - nx;
    if (v2 < 16 * NEB) {                           // ---- c fragments (hi+lo) ----
        int kg = v2 >> 7, eb = v2 & (NEB - 1);
        int k = eb * 32 + l31;
        float f[8] = {0,0,0,0,0,0,0,0};
        if (k < K) {
            int row = ridx[k];
            int f0 = kg * 4 + hi * 2;
            float4 a = cb4[(size_t)row * D4 + f0];
            float4 b = cb4[(size_t)row * D4 + f0 + 1];
            f[0]=a.x; f[1]=a.y; f[2]=a.z; f[3]=a.w;
            f[4]=b.x; f[5]=b.y; f[6]=b.z; f[7]=b.w;
        }
        ushort uh[8], ul[8];
        #pragma unroll
        for (int i = 0; i < 8; ++i) {
            ushort hb = f2bf_rn(f[i]);
            uh[i] = hb;
            ul[i] = f2bf_rn(f[i] - bf2f(hb));
        }
        uint4 oh = {pack2(uh[0],uh[1]), pack2(uh[2],uh[3]),
                    pack2(uh[4],uh[5]), pack2(uh[6],uh[7])};
        uint4 ol = {pack2(ul[0],ul[1]), pack2(ul[2],ul[3]),
                    pack2(ul[4],ul[5]), pack2(ul[6],ul[7])};
        *(uint4*)&cpF[((size_t)kg * NEB + eb) * 512 + lane * 8]        = oh;
        *(uint4*)&cpF[((size_t)(kg + 16) * NEB + eb) * 512 + lane * 8] = ol;
        return;
    }
    int k = v2 - 16 * NEB;                         // ---- c2 ----
    if (k >= KPAD) return;
    double s = 0.0;
    if (k < K) {
        int row = ridx[k];
        float4 vv = cb4[(size_t)row * D4 + lane];
        s = (double)vv.x * vv.x + (double)vv.y * vv.y
          + (double)vv.z * vv.z + (double)vv.w * vv.w;
    }
    #pragma unroll
    for (int off = 32; off; off >>= 1) s += __shfl_xor(s, off, 64);
    if (lane == 0) c2[k] = (k < K) ? (float)s : INFINITY;
}

// ---------------------------------------------------------------------------
// k1_mfma v7: 4 waves (256 thr), 128 tok x 128 ent per block, NSPLIT=32.
// A (entries) staged via global_load_lds into 3x8KB buffers; B (tokens)
// loaded DIRECTLY global->VGPR from the pre-swizzled xpF (bit-identical to
// the staged path) with 1-step prefetch issued after the MFMA cluster
// (WAR-safe). ds_read volume halves vs r8; 4-wave barrier groups + small
// LDS (25KB) let several independent blocks drift per CU.
__global__ __launch_bounds__(256, 4)
void k1_mfma(const ushort* __restrict__ xpF, const ushort* __restrict__ cpF,
             const float* __restrict__ c2,
             float* __restrict__ pb1, float* __restrict__ pb2,
             int* __restrict__ pbi, int Ntok) {
    __shared__ __align__(16) ushort lds[3 * BUFU];   // 24 KiB
    __shared__ float c2all[KSPAN];                   // 0.5 KiB

    const int tid  = threadIdx.x;
    const int w    = tid >> 6;         // 0..3
    const int lane = tid & 63;
    const int we   = w >> 1;           // 0..1: entry half (64 entries)
    const int wn   = w & 1;            // 0..1: token half (64 tokens)
    const int hi   = lane >> 5;
    const int l31  = lane & 31;
    const int NTB  = Ntok >> 5;

    const int raw = (int)blockIdx.x;
    const int kb  = raw & (NSPLIT - 1);
    const int m0  = (raw >> 5) * TMTOK;
    const int tb0 = m0 >> 5;
    const int e0s = kb * KSPAN;
    const int eb0 = e0s >> 5;          // kb*4

    if (tid < KSPAN) c2all[tid] = c2[e0s + tid];

    // A staging: 8 frags / 4 waves = 2 gld_lds per wave per step.
    auto stageA = [&](int g, int buf) {
        ushort* A = &lds[buf * BUFU];
        #pragma unroll
        for (int j = 0; j < 2; ++j) {
            int idx = w * 2 + j;               // 0..7
            int hl = idx >> 2, ebl = idx & 3;
            GLD16(cpF + ((size_t)(g + hl * 16) * NEB + eb0 + ebl) * 512 + lane * 8,
                  &A[idx * 512]);
        }
    };
    // B fragment global->reg address
    auto bptr = [&](int g, int tt) -> const bf16x8* {
        return (const bf16x8*)&xpF[((size_t)g * NTB + tb0 + wn * 2 + tt) * 512 + lane * 8];
    };

    f32x16 acc[2][2];
    #pragma unroll
    for (int et = 0; et < 2; ++et)
        #pragma unroll
        for (int tt = 0; tt < 2; ++tt) acc[et][tt] = zero16();

    // prologue: B(0) regs, stage A(0), A(1); wait B(0)+A(0) (leave A(1) flying)
    bf16x8 bh[2], bl[2];
    #pragma unroll
    for (int tt = 0; tt < 2; ++tt) { bh[tt] = *bptr(0, tt); bl[tt] = *bptr(16, tt); }
    stageA(0, 0);
    stageA(1, 1);
    asm volatile("s_waitcnt vmcnt(2)" ::: "memory");
    __builtin_amdgcn_sched_barrier(0);
    __builtin_amdgcn_s_barrier();
    __builtin_amdgcn_sched_barrier(0);

    int bufr = 0;
    for (int s = 0; s < NSTEPK; ++s) {
        const ushort* A = &lds[bufr * BUFU];
        bf16x8 ah[2], al[2];
        #pragma unroll
        for (int et = 0; et < 2; ++et) {
            ah[et] = *(const bf16x8*)&A[(we * 2 + et) * 512 + lane * 8];
            al[et] = *(const bf16x8*)&A[(4 + we * 2 + et) * 512 + lane * 8];
        }

        __builtin_amdgcn_s_setprio(1);
        #pragma unroll
        for (int et = 0; et < 2; ++et)
            #pragma unroll
            for (int tt = 0; tt < 2; ++tt) {
                acc[et][tt] = __builtin_amdgcn_mfma_f32_32x32x16_bf16(
                    ah[et], bh[tt], acc[et][tt], 0, 0, 0);
                acc[et][tt] = __builtin_amdgcn_mfma_f32_32x32x16_bf16(
                    al[et], bh[tt], acc[et][tt], 0, 0, 0);
                acc[et][tt] = __builtin_amdgcn_mfma_f32_32x32x16_bf16(
                    ah[et], bl[tt], acc[et][tt], 0, 0, 0);
            }
        __builtin_amdgcn_s_setprio(0);

        // prefetch B(s+1) into the (now dead) b regs, then stage A(s+2).
        int bp = s + 1; if (bp > NSTEPK - 1) bp = NSTEPK - 1;   // uniform counts
        int sp = s + 2; if (sp > NSTEPK - 1) sp = NSTEPK - 1;
        bf16x8 nh0 = *bptr(bp, 0), nh1 = *bptr(bp, 1);
        bf16x8 nl0 = *bptr(bp + 16, 0), nl1 = *bptr(bp + 16, 1);
        int bufc = bufr + 2; if (bufc >= 3) bufc -= 3;
        stageA(sp, bufc);

        asm volatile("s_waitcnt vmcnt(6)" ::: "memory");   // A(s+1) landed;
        __builtin_amdgcn_sched_barrier(0);                 // B(s+1)+A(s+2) fly
        __builtin_amdgcn_s_barrier();                      // buf[s] reads done
        __builtin_amdgcn_sched_barrier(0);

        bh[0] = nh0; bh[1] = nh1; bl[0] = nl0; bl[1] = nl1;
        bufr = bufr + 1; if (bufr >= 3) bufr = 0;
    }

    // epilogue: scores + branchless top-2 (lexicographic tie-break)
    float b1[2] = {INFINITY, INFINITY}, b2[2] = {INFINITY, INFINITY};
    int   bi[2] = {0, 0};
    #pragma unroll
    for (int tt = 0; tt < 2; ++tt)
        #pragma unroll
        for (int et = 0; et < 2; ++et)
            #pragma unroll
            for (int r = 0; r < 16; ++r) {
                int rl = we * 64 + et * 32 + (r & 3) + 8 * (r >> 2) + 4 * hi;
                float sc = fmaf(-2.f, acc[et][tt][r], c2all[rl]);
                int   k  = e0s + rl;
                bool better = (sc < b1[tt]) || (sc == b1[tt] && k < bi[tt]);
                float nb2 = better ? b1[tt] : fminf(b2[tt], sc);
                b1[tt] = better ? sc : b1[tt];
                bi[tt] = better ? k  : bi[tt];
                b2[tt] = nb2;
            }

    // merge lane <-> lane^32 (complementary entry rows, same token col)
    #pragma unroll
    for (int tt = 0; tt < 2; ++tt) {
        float o1 = __shfl_xor(b1[tt], 32, 64);
        float o2 = __shfl_xor(b2[tt], 32, 64);
        int   oi = __shfl_xor(bi[tt], 32, 64);
        if (o1 < b1[tt] || (o1 == b1[tt] && oi < bi[tt])) {
            b2[tt] = fminf(b1[tt], o2); b1[tt] = o1; bi[tt] = oi;
        } else b2[tt] = fminf(b2[tt], o1);
    }

    __syncthreads();                       // drains tail loads; LDS reusable
    float* s1 = (float*)lds;               // [we 0..1][128 tokens]
    float* s2 = s1 + 256;
    int*   si = (int*)(s2 + 256);
    if (hi == 0) {
        #pragma unroll
        for (int tt = 0; tt < 2; ++tt) {
            int tl = wn * 64 + tt * 32 + l31;
            s1[we * 128 + tl] = b1[tt];
            s2[we * 128 + tl] = b2[tt];
            si[we * 128 + tl] = bi[tt];
        }
    }
    __syncthreads();
    if (tid < TMTOK) {
        float v1 = s1[tid], v2 = s2[tid]; int vi = si[tid];
        float u1 = s1[128 + tid], u2 = s2[128 + tid];
        int   ui = si[128 + tid];
        if (u1 < v1 || (u1 == v1 && ui < vi)) { v2 = fminf(v1, u2); v1 = u1; vi = ui; }
        else                                  { v2 = fminf(v2, u1); }
        size_t o = (size_t)kb * Ntok + m0 + tid;
        pb1[o] = v1; pb2[o] = v2; pbi[o] = vi;
    }
}

// ---------------------------------------------------------------------------
// k2: combine splits per token; provisional global idx; flag near-ties.
__global__ __launch_bounds__(256)
void k2_combine(const float* __restrict__ pb1, const float* __restrict__ pb2,
                const int* __restrict__ pbi, const int* __restrict__ ridx,
                int* __restrict__ gidx, int* __restrict__ tlist,
                int* __restrict__ cnt, int Ntok, int nsplit) {
    int t = blockIdx.x * 256 + threadIdx.x;
    if (t >= Ntok) return;
    float v1 = INFINITY, v2 = INFINITY; int vi = 0x7fffffff;
    for (int kb = 0; kb < nsplit; ++kb) {
        size_t o = (size_t)kb * Ntok + t;
        float u1 = pb1[o], u2 = pb2[o]; int ui = pbi[o];
        if (u1 < v1 || (u1 == v1 && ui < vi)) { v2 = fminf(v1, u2); v1 = u1; vi = ui; }
        else                                  { v2 = fminf(v2, u1); }
    }
    gidx[t] = ridx[vi];
    if (v2 - v1 < TAU) {
        int pos = atomicAdd(cnt, 1);
        tlist[pos] = t;
    }
}

// ---------------------------------------------------------------------------
// k_recheck: exact f64 argmin, lexicographic tie-break, flagged tokens only.
__global__ __launch_bounds__(256)
void k_recheck(const float4* __restrict__ x4, const float4* __restrict__ cb4,
               const int* __restrict__ ridx, const int* __restrict__ tlist,
               const int* __restrict__ cnt, int* __restrict__ gidx, int K) {
    __shared__ float4 xls[D4];
    __shared__ double rv[256];
    __shared__ int    rix[256];
    const int tid = threadIdx.x;
    const int n   = *cnt;
    for (int fi = blockIdx.x; fi < n; fi += gridDim.x) {
        int t = tlist[fi];
        if (tid < D4) xls[tid] = x4[(size_t)t * D4 + tid];
        __syncthreads();
        double bv = INFINITY; int bi = 0x7fffffff;
        for (int k = tid; k < K; k += 256) {
            const float4* cr = cb4 + (size_t)ridx[k] * D4;
            double s = 0.0, cc = 0.0;
            #pragma unroll 4
            for (int d = 0; d < D4; ++d) {
                float4 cv = cr[d], xv = xls[d];
                s  = fma((double)cv.x, (double)xv.x, s);
                s  = fma((double)cv.y, (double)xv.y, s);
                s  = fma((double)cv.z, (double)xv.z, s);
                s  = fma((double)cv.w, (double)xv.w, s);
                cc = fma((double)cv.x, (double)cv.x, cc);
                cc = fma((double)cv.y, (double)cv.y, cc);
                cc = fma((double)cv.z, (double)cv.z, cc);
                cc = fma((double)cv.w, (double)cv.w, cc);
            }
            double sc = cc - 2.0 * s;
            if (sc < bv || (sc == bv && k < bi)) { bv = sc; bi = k; }
        }
        rv[tid] = bv; rix[tid] = bi;
        __syncthreads();
        for (int st = 128; st; st >>= 1) {
            if (tid < st) {
                double u = rv[tid + st]; int ui = rix[tid + st];
                if (u < rv[tid] || (u == rv[tid] && ui < rix[tid])) {
                    rv[tid] = u; rix[tid] = ui;
                }
            }
            __syncthreads();
        }
        if (tid == 0) gidx[t] = ridx[rix[0]];
        __syncthreads();
    }
}

// ---------------------------------------------------------------------------
// k3: gather codebook row per token, write tokens + float index + sq-err sum.
__global__ __launch_bounds__(256)
void k3_gather(const float4* __restrict__ x4, const float4* __restrict__ cb4,
               const int* __restrict__ gidx, float4* __restrict__ out_tok,
               float* __restrict__ out_idx, float* __restrict__ tok_loss,
               int Ntok) {
    int t    = (int)(blockIdx.x * 4 + (threadIdx.x >> 6));
    int lane = threadIdx.x & 63;
    if (t >= Ntok) return;
    int g = gidx[t];
    float4 cv = cb4[(size_t)g * D4 + lane];
    float4 xv = x4[(size_t)t * D4 + lane];
    out_tok[(size_t)t * D4 + lane] = cv;
    if (lane == 0) out_idx[t] = (float)g;
    float dx = cv.x - xv.x, dy = cv.y - xv.y, dz = cv.z - xv.z, dw = cv.w - xv.w;
    float s = dx * dx + dy * dy + dz * dz + dw * dw;
    #pragma unroll
    for (int off = 32; off; off >>= 1) s += __shfl_xor(s, off, 64);
    if (lane == 0) tok_loss[t] = s;
}

// ---------------------------------------------------------------------------
// k4: deterministic fixed-order loss mean (single block).
__global__ __launch_bounds__(256)
void k4_loss(const float* __restrict__ tok_loss, float* __restrict__ out_loss,
             int Ntok, double inv_total) {
    __shared__ double sm[256];
    double s = 0.0;
    for (int i = threadIdx.x; i < Ntok; i += 256) s += (double)tok_loss[i];
    sm[threadIdx.x] = s;
    __syncthreads();
    for (int st = 128; st; st >>= 1) {
        if ((int)threadIdx.x < st) sm[threadIdx.x] += sm[threadIdx.x + st];
        __syncthreads();
    }
    if (threadIdx.x == 0) *out_loss = (float)(sm[0] * inv_total);
}

// ---------------------------------------------------------------------------
// ---- f32 fallback path (round-2 proven) — only if ws too small ----
__global__ __launch_bounds__(256)
void k0_c2(const float4* __restrict__ cb4, const int* __restrict__ ridx,
           float* __restrict__ c2, int K, int kpad) {
    int k    = (int)(blockIdx.x * 4 + (threadIdx.x >> 6));
    int lane = threadIdx.x & 63;
    if (k >= kpad) return;
    double s = 0.0;
    if (k < K) {
        int row = ridx[k];
        float4 v = cb4[(size_t)row * D4 + lane];
        s = (double)v.x * v.x + (double)v.y * v.y
          + (double)v.z * v.z + (double)v.w * v.w;
    }
    #pragma unroll
    for (int off = 32; off; off >>= 1) s += __shfl_xor(s, off, 64);
    if (lane == 0) c2[k] = (k < K) ? (float)s : INFINITY;
}

__global__ __launch_bounds__(256, 2)
void fk1_argmin(const float4* __restrict__ x4, const float4* __restrict__ cb4,
                const int* __restrict__ ridx, const float* __restrict__ c2,
                float* __restrict__ pb1, float* __restrict__ pb2,
                int* __restrict__ pbi, int Ntok, int K, int kspan) {
    __shared__ float4 xs4[128 * 16];
    __shared__ float4 cs4[128 * 16];
    __shared__ float  c2_t[128];
    const int tid = threadIdx.x;
    const int r = tid >> 4, c = tid & 15;
    const int m0 = blockIdx.x * 128;
    const int kbase0 = blockIdx.y * kspan;
    float b1[8], b2[8]; int bi[8];
    #pragma unroll
    for (int i = 0; i < 8; ++i) { b1[i] = INFINITY; b2[i] = INFINITY; bi[i] = 0; }
    for (int t = 0; t < 8; ++t) {
        const int kbase = kbase0 + t * 128;
        if (kbase >= K) break;
        __syncthreads();
        if (tid < 128) c2_t[tid] = c2[kbase + tid];
        int cidx[8];
        #pragma unroll
        for (int q = 0; q < 8; ++q) {
            int k = kbase + 16 * q + r;
            cidx[q] = ridx[(k < K) ? k : 0];
        }
        float acc[8][8];
        #pragma unroll
        for (int i = 0; i < 8; ++i)
            #pragma unroll
            for (int j = 0; j < 8; ++j) acc[i][j] = 0.f;
        for (int ch = 0; ch < 4; ++ch) {
            __syncthreads();
            #pragma unroll
            for (int q = 0; q < 8; ++q) {
                int row = 16 * q + r;
                int p   = c ^ (row & 7);
                xs4[row * 16 + p] = x4[(size_t)(m0 + row) * D4 + ch * 16 + c];
                cs4[row * 16 + p] = cb4[(size_t)cidx[q] * D4 + ch * 16 + c];
            }
            __syncthreads();
            #pragma unroll 2
            for (int f = 0; f < 16; ++f) {
                float4 xf[8];
                #pragma unroll
                for (int i = 0; i < 8; ++i) xf[i] = xs4[(8 * r + i) * 16 + (f ^ i)];
                #pragma unroll
                for (int j = 0; j < 8; ++j) {
                    float4 cf = cs4[(c + 16 * j) * 16 + (f ^ (c & 7))];
                    #pragma unroll
                    for (int i = 0; i < 8; ++i) {
                        acc[i][j] = fmaf(xf[i].x, cf.x, acc[i][j]);
                        acc[i][j] = fmaf(xf[i].y, cf.y, acc[i][j]);
                        acc[i][j] = fmaf(xf[i].z, cf.z, acc[i][j]);
                        acc[i][j] = fmaf(xf[i].w, cf.w, acc[i][j]);
                    }
                }
            }
        }
        #pragma unroll
        for (int j = 0; j < 8; ++j) {
            float c2v = c2_t[c + 16 * j];
            int   k   = kbase + c + 16 * j;
            #pragma unroll
            for (int i = 0; i < 8; ++i) {
                float sc = fmaf(-2.f, acc[i][j], c2v);
                if (sc < b1[i]) { b2[i] = b1[i]; b1[i] = sc; bi[i] = k; }
                else            { b2[i] = fminf(b2[i], sc); }
            }
        }
    }
    __syncthreads();
    float* s1 = (float*)xs4;
    float* s2 = s1 + 128 * 16;
    int*   si = (int*)cs4;
    #pragma unroll
    for (int i = 0; i < 8; ++i) {
        int row = 8 * r + i;
        s1[row * 16 + c] = b1[i]; s2[row * 16 + c] = b2[i]; si[row * 16 + c] = bi[i];
    }
    __syncthreads();
    if (tid < 128) {
        float v1 = s1[tid * 16], v2 = s2[tid * 16];
        int   vi = si[tid * 16];
        #pragma unroll
        for (int cc = 1; cc < 16; ++cc) {
            float u1 = s1[tid * 16 + cc], u2 = s2[tid * 16 + cc];
            int   ui = si[tid * 16 + cc];
            if (u1 < v1 || (u1 == v1 && ui < vi)) { v2 = fminf(v1, u2); v1 = u1; vi = ui; }
            else                                  { v2 = fminf(v2, u1); }
        }
        size_t o = (size_t)blockIdx.y * Ntok + m0 + tid;
        pb1[o] = v1; pb2[o] = v2; pbi[o] = vi;
    }
}

// ---------------------------------------------------------------------------
extern "C" void kernel_launch(void* const* d_in, const int* in_sizes, int n_in,
                              void* d_out, int out_size, void* d_ws, size_t ws_size,
                              hipStream_t stream) {
    const float* x    = (const float*)d_in[0];
    const float* cb   = (const float*)d_in[1];
    const int*   ridx = (const int*)d_in[2];

    const int Ntok = in_sizes[0] / D;          // 16384
    const int K    = in_sizes[2];              // 3686

    float* out      = (float*)d_out;
    float* out_loss = out + (size_t)Ntok * D;
    float* out_idx  = out + (size_t)Ntok * D + 1;

    const float4* x4  = (const float4*)x;
    const float4* cb4 = (const float4*)cb;

    auto up = [](size_t v) { return (v + 255) & ~(size_t)255; };

    size_t need = 256 + up((size_t)KPAD * 512 * 2) + up((size_t)KPAD * 4)
                + 3 * up((size_t)NSPLIT * Ntok * 4) + 3 * up((size_t)Ntok * 4);

    const int gblocks = (Ntok + 3) / 4;
    const double inv_total = 1.0 / ((double)Ntok * (double)D);

    if (ws_size >= need && (Ntok & 127) == 0) {
        // ---------------- MFMA pipeline path ----------------
        char* w = (char*)d_ws;
        int*    cnt   = (int*)w;    w += 256;
        ushort* cpF   = (ushort*)w; w += up((size_t)KPAD * 512 * 2);
        float*  c2    = (float*)w;  w += up((size_t)KPAD * 4);
        float*  pb1   = (float*)w;  w += up((size_t)NSPLIT * Ntok * 4);
        float*  pb2   = (float*)w;  w += up((size_t)NSPLIT * Ntok * 4);
        int*    pbi   = (int*)w;    w += up((size_t)NSPLIT * Ntok * 4);
        int*    gidx  = (int*)w;    w += up((size_t)Ntok * 4);
        int*    tlist = (int*)w;    w += up((size_t)Ntok * 4);
        float*  tl    = (float*)w;

        ushort* xpF = (ushort*)d_out;   // 16.8 MB: exact fit in out_tok region

        const int nwav = 16 * (Ntok >> 5) + 16 * NEB + KPAD;

        hipMemsetAsync(cnt, 0, 4, stream);
        p01_pack<<<dim3((nwav + 3) / 4), dim3(256), 0, stream>>>(
            x4, cb4, ridx, xpF, cpF, c2, Ntok, K);
        k1_mfma<<<dim3((Ntok / TMTOK) * NSPLIT), dim3(256), 0, stream>>>(
            xpF, cpF, c2, pb1, pb2, pbi, Ntok);
        k2_combine<<<dim3((Ntok + 255) / 256), dim3(256), 0, stream>>>(
            pb1, pb2, pbi, ridx, gidx, tlist, cnt, Ntok, NSPLIT);
        k_recheck<<<dim3(256), dim3(256), 0, stream>>>(
            x4, cb4, ridx, tlist, cnt, gidx, K);
        k3_gather<<<dim3(gblocks), dim3(256), 0, stream>>>(
            x4, cb4, gidx, (float4*)out, out_idx, tl, Ntok);
        k4_loss<<<dim3(1), dim3(256), 0, stream>>>(tl, out_loss, Ntok, inv_total);
    } else {
        // ---------------- f32 fallback (round-2 proven) ----------------
        const int kpad  = 4096;
        const int kspan = 1024;
        char* w = (char*)d_ws;
        int*   cnt   = (int*)w;    w += 256;
        float* c2    = (float*)w;  w += up((size_t)kpad * 4);
        float* pb1   = (float*)w;  w += up((size_t)4 * Ntok * 4);
        float* pb2   = (float*)w;  w += up((size_t)4 * Ntok * 4);
        int*   pbi   = (int*)w;    w += up((size_t)4 * Ntok * 4);
        int*   gidx  = (int*)w;    w += up((size_t)Ntok * 4);
        int*   tlist = (int*)w;    w += up((size_t)Ntok * 4);
        float* tl    = (float*)w;

        hipMemsetAsync(cnt, 0, 4, stream);
        k0_c2<<<dim3(kpad / 4), dim3(256), 0, stream>>>(cb4, ridx, c2, K, kpad);
        fk1_argmin<<<dim3(Ntok / 128, 4), dim3(256), 0, stream>>>(
            x4, cb4, ridx, c2, pb1, pb2, pbi, Ntok, K, kspan);
        k2_combine<<<dim3((Ntok + 255) / 256), dim3(256), 0, stream>>>(
            pb1, pb2, pbi, ridx, gidx, tlist, cnt, Ntok, 4);
        k_recheck<<<dim3(256), dim3(256), 0, stream>>>(
            x4, cb4, ridx, tlist, cnt, gidx, K);
        k3_gather<<<dim3(gblocks), dim3(256), 0, stream>>>(
            x4, cb4, gidx, (float4*)out, out_idx, tl, Ntok);
        k4_loss<<<dim3(1), dim3(256), 0, stream>>>(tl, out_loss, Ntok, inv_total);
    }
}

// Round 14
// 327.286 us; speedup vs baseline: 1.0023x; 1.0023x over previous
//
#include <hip/hip_runtime.h>
#include <math.h>

// Problem geometry: D=256 fixed; N, K from in_sizes.
#define D      256
#define D4     64
#define TAU    6.0e-3f   // near-tie margin; bf16-3-product score error ~2e-3

// ---- MFMA-path geometry (round 10: 4-wave blocks, B via registers) ----
#define KPAD    4096     // padded subsampled-codebook size
#define NEB     128      // entry blocks of 32 (KPAD/32)
#define NSPLIT  32       // entry splits; kb = blockIdx.x & 31
#define KSPAN   128      // entries per block
#define TMTOK   128      // tokens per block
#define NSTEPK  16       // k16-groups (D/16)
#define AFRAGS  8        // per step: 4 eb x {hi,lo}  (entries staged to LDS)
#define BUFU    (AFRAGS * 512)              // ushorts per LDS buffer (8 KiB)

typedef short bf16x8 __attribute__((ext_vector_type(8)));
typedef float f32x16 __attribute__((ext_vector_type(16)));

#define GLD16(g, l) __builtin_amdgcn_global_load_lds( \
    (const __attribute__((address_space(1))) void*)(g), \
    (__attribute__((address_space(3))) void*)(l), 16, 0, 0)

__device__ inline ushort f2bf_rn(float f) {           // RNE f32 -> bf16 bits
    unsigned u = __float_as_uint(f);
    unsigned r = (u + 0x7fffu + ((u >> 16) & 1u)) >> 16;
    return (ushort)r;
}
__device__ inline float bf2f(ushort u) { return __uint_as_float(((unsigned)u) << 16); }
__device__ inline f32x16 zero16() {
    f32x16 z = {0,0,0,0,0,0,0,0,0,0,0,0,0,0,0,0};
    return z;
}
__device__ inline unsigned pack2(ushort a, ushort b) {
    return (unsigned)a | ((unsigned)b << 16);
}

// ---------------------------------------------------------------------------
// p01 v2: fragment-major pack, hi+lo fused (one read -> two plane writes).
// xpF[kg][tb][512], cpF[kg][eb][512]: kg<16 bf16hi, kg>=16 bf16lo of kg-16.
// Fragment: lane l -> row blk*32+(l&31), k'' = (l>>5)*8..+8 contiguous.
// Plus c2[k] (f64-exact, +inf pads).
__global__ __launch_bounds__(256)
void p01_pack(const float4* __restrict__ x4, const float4* __restrict__ cb4,
              const int* __restrict__ ridx, ushort* __restrict__ xpF,
              ushort* __restrict__ cpF, float* __restrict__ c2,
              int Ntok, int K) {
    const int v    = (int)(blockIdx.x * 4 + (threadIdx.x >> 6));
    const int lane = threadIdx.x & 63;
    const int l31  = lane & 31, hi = lane >> 5;
    const int NTB  = Ntok >> 5;
    const int nx   = 16 * NTB;

    if (v < nx) {                                  // ---- x fragments (hi+lo) ----
        int kg = v / NTB, tb = v - kg * NTB;
        int token = tb * 32 + l31;
        int f0 = kg * 4 + hi * 2;                  // float4 index
        float4 a = x4[(size_t)token * D4 + f0];
        float4 b = x4[(size_t)token * D4 + f0 + 1];
        float f[8] = {a.x, a.y, a.z, a.w, b.x, b.y, b.z, b.w};
        ushort uh[8], ul[8];
        #pragma unroll
        for (int i = 0; i < 8; ++i) {
            ushort hb = f2bf_rn(f[i]);
            uh[i] = hb;
            ul[i] = f2bf_rn(f[i] - bf2f(hb));
        }
        uint4 oh = {pack2(uh[0],uh[1]), pack2(uh[2],uh[3]),
                    pack2(uh[4],uh[5]), pack2(uh[6],uh[7])};
        uint4 ol = {pack2(ul[0],ul[1]), pack2(ul[2],ul[3]),
                    pack2(ul[4],ul[5]), pack2(ul[6],ul[7])};
        *(uint4*)&xpF[((size_t)kg * NTB + tb) * 512 + lane * 8]        = oh;
        *(uint4*)&xpF[((size_t)(kg + 16) * NTB + tb) * 512 + lane * 8] = ol;
        return;
    }
    int v2 = v - nx;
    if (v2 < 16 * NEB) {                           // ---- c fragments (hi+lo) ----
        int kg = v2 >> 7, eb = v2 & (NEB - 1);
        int k = eb * 32 + l31;
        float f[8] = {0,0,0,0,0,0,0,0};
        if (k < K) {
            int row = ridx[k];
            int f0 = kg * 4 + hi * 2;
            float4 a = cb4[(size_t)row * D4 + f0];
            float4 b = cb4[(size_t)row * D4 + f0 + 1];
            f[0]=a.x; f[1]=a.y; f[2]=a.z; f[3]=a.w;
            f[4]=b.x; f[5]=b.y; f[6]=b.z; f[7]=b.w;
        }
        ushort uh[8], ul[8];
        #pragma unroll
        for (int i = 0; i < 8; ++i) {
            ushort hb = f2bf_rn(f[i]);
            uh[i] = hb;
            ul[i] = f2bf_rn(f[i] - bf2f(hb));
        }
        uint4 oh = {pack2(uh[0],uh[1]), pack2(uh[2],uh[3]),
                    pack2(uh[4],uh[5]), pack2(uh[6],uh[7])};
        uint4 ol = {pack2(ul[0],ul[1]), pack2(ul[2],ul[3]),
                    pack2(ul[4],ul[5]), pack2(ul[6],ul[7])};
        *(uint4*)&cpF[((size_t)kg * NEB + eb) * 512 + lane * 8]        = oh;
        *(uint4*)&cpF[((size_t)(kg + 16) * NEB + eb) * 512 + lane * 8] = ol;
        return;
    }
    int k = v2 - 16 * NEB;                         // ---- c2 ----
    if (k >= KPAD) return;
    double s = 0.0;
    if (k < K) {
        int row = ridx[k];
        float4 vv = cb4[(size_t)row * D4 + lane];
        s = (double)vv.x * vv.x + (double)vv.y * vv.y
          + (double)vv.z * vv.z + (double)vv.w * vv.w;
    }
    #pragma unroll
    for (int off = 32; off; off >>= 1) s += __shfl_xor(s, off, 64);
    if (lane == 0) c2[k] = (k < K) ? (float)s : INFINITY;
}

// ---------------------------------------------------------------------------
// k1_mfma v7: 4 waves (256 thr), 128 tok x 128 ent per block, NSPLIT=32.
// A (entries) staged via global_load_lds into 3x8KB buffers; B (tokens)
// loaded DIRECTLY global->VGPR from the pre-swizzled xpF (bit-identical to
// the staged path) with 1-step prefetch issued after the MFMA cluster
// (WAR-safe). ds_read volume halves vs r8; 4-wave barrier groups + small
// LDS (25KB) let several independent blocks drift per CU.
__global__ __launch_bounds__(256, 4)
void k1_mfma(const ushort* __restrict__ xpF, const ushort* __restrict__ cpF,
             const float* __restrict__ c2,
             float* __restrict__ pb1, float* __restrict__ pb2,
             int* __restrict__ pbi, int Ntok) {
    __shared__ __align__(16) ushort lds[3 * BUFU];   // 24 KiB
    __shared__ float c2all[KSPAN];                   // 0.5 KiB

    const int tid  = threadIdx.x;
    const int w    = tid >> 6;         // 0..3
    const int lane = tid & 63;
    const int we   = w >> 1;           // 0..1: entry half (64 entries)
    const int wn   = w & 1;            // 0..1: token half (64 tokens)
    const int hi   = lane >> 5;
    const int l31  = lane & 31;
    const int NTB  = Ntok >> 5;

    const int raw = (int)blockIdx.x;
    const int kb  = raw & (NSPLIT - 1);
    const int m0  = (raw >> 5) * TMTOK;
    const int tb0 = m0 >> 5;
    const int e0s = kb * KSPAN;
    const int eb0 = e0s >> 5;          // kb*4

    if (tid < KSPAN) c2all[tid] = c2[e0s + tid];

    // A staging: 8 frags / 4 waves = 2 gld_lds per wave per step.
    auto stageA = [&](int g, int buf) {
        ushort* A = &lds[buf * BUFU];
        #pragma unroll
        for (int j = 0; j < 2; ++j) {
            int idx = w * 2 + j;               // 0..7
            int hl = idx >> 2, ebl = idx & 3;
            GLD16(cpF + ((size_t)(g + hl * 16) * NEB + eb0 + ebl) * 512 + lane * 8,
                  &A[idx * 512]);
        }
    };
    // B fragment global->reg address
    auto bptr = [&](int g, int tt) -> const bf16x8* {
        return (const bf16x8*)&xpF[((size_t)g * NTB + tb0 + wn * 2 + tt) * 512 + lane * 8];
    };

    f32x16 acc[2][2];
    #pragma unroll
    for (int et = 0; et < 2; ++et)
        #pragma unroll
        for (int tt = 0; tt < 2; ++tt) acc[et][tt] = zero16();

    // prologue: B(0) regs, stage A(0), A(1); wait B(0)+A(0) (leave A(1) flying)
    bf16x8 bh[2], bl[2];
    #pragma unroll
    for (int tt = 0; tt < 2; ++tt) { bh[tt] = *bptr(0, tt); bl[tt] = *bptr(16, tt); }
    stageA(0, 0);
    stageA(1, 1);
    asm volatile("s_waitcnt vmcnt(2)" ::: "memory");
    __builtin_amdgcn_sched_barrier(0);
    __builtin_amdgcn_s_barrier();
    __builtin_amdgcn_sched_barrier(0);

    int bufr = 0;
    for (int s = 0; s < NSTEPK; ++s) {
        const ushort* A = &lds[bufr * BUFU];
        bf16x8 ah[2], al[2];
        #pragma unroll
        for (int et = 0; et < 2; ++et) {
            ah[et] = *(const bf16x8*)&A[(we * 2 + et) * 512 + lane * 8];
            al[et] = *(const bf16x8*)&A[(4 + we * 2 + et) * 512 + lane * 8];
        }

        __builtin_amdgcn_s_setprio(1);
        #pragma unroll
        for (int et = 0; et < 2; ++et)
            #pragma unroll
            for (int tt = 0; tt < 2; ++tt) {
                acc[et][tt] = __builtin_amdgcn_mfma_f32_32x32x16_bf16(
                    ah[et], bh[tt], acc[et][tt], 0, 0, 0);
                acc[et][tt] = __builtin_amdgcn_mfma_f32_32x32x16_bf16(
                    al[et], bh[tt], acc[et][tt], 0, 0, 0);
                acc[et][tt] = __builtin_amdgcn_mfma_f32_32x32x16_bf16(
                    ah[et], bl[tt], acc[et][tt], 0, 0, 0);
            }
        __builtin_amdgcn_s_setprio(0);

        // prefetch B(s+1) into the (now dead) b regs, then stage A(s+2).
        int bp = s + 1; if (bp > NSTEPK - 1) bp = NSTEPK - 1;   // uniform counts
        int sp = s + 2; if (sp > NSTEPK - 1) sp = NSTEPK - 1;
        bf16x8 nh0 = *bptr(bp, 0), nh1 = *bptr(bp, 1);
        bf16x8 nl0 = *bptr(bp + 16, 0), nl1 = *bptr(bp + 16, 1);
        int bufc = bufr + 2; if (bufc >= 3) bufc -= 3;
        stageA(sp, bufc);

        asm volatile("s_waitcnt vmcnt(6)" ::: "memory");   // A(s+1) landed;
        __builtin_amdgcn_sched_barrier(0);                 // B(s+1)+A(s+2) fly
        __builtin_amdgcn_s_barrier();                      // buf[s] reads done
        __builtin_amdgcn_sched_barrier(0);

        bh[0] = nh0; bh[1] = nh1; bl[0] = nl0; bl[1] = nl1;
        bufr = bufr + 1; if (bufr >= 3) bufr = 0;
    }

    // epilogue: scores + branchless top-2 (lexicographic tie-break)
    float b1[2] = {INFINITY, INFINITY}, b2[2] = {INFINITY, INFINITY};
    int   bi[2] = {0, 0};
    #pragma unroll
    for (int tt = 0; tt < 2; ++tt)
        #pragma unroll
        for (int et = 0; et < 2; ++et)
            #pragma unroll
            for (int r = 0; r < 16; ++r) {
                int rl = we * 64 + et * 32 + (r & 3) + 8 * (r >> 2) + 4 * hi;
                float sc = fmaf(-2.f, acc[et][tt][r], c2all[rl]);
                int   k  = e0s + rl;
                bool better = (sc < b1[tt]) || (sc == b1[tt] && k < bi[tt]);
                float nb2 = better ? b1[tt] : fminf(b2[tt], sc);
                b1[tt] = better ? sc : b1[tt];
                bi[tt] = better ? k  : bi[tt];
                b2[tt] = nb2;
            }

    // merge lane <-> lane^32 (complementary entry rows, same token col)
    #pragma unroll
    for (int tt = 0; tt < 2; ++tt) {
        float o1 = __shfl_xor(b1[tt], 32, 64);
        float o2 = __shfl_xor(b2[tt], 32, 64);
        int   oi = __shfl_xor(bi[tt], 32, 64);
        if (o1 < b1[tt] || (o1 == b1[tt] && oi < bi[tt])) {
            b2[tt] = fminf(b1[tt], o2); b1[tt] = o1; bi[tt] = oi;
        } else b2[tt] = fminf(b2[tt], o1);
    }

    __syncthreads();                       // drains tail loads; LDS reusable
    float* s1 = (float*)lds;               // [we 0..1][128 tokens]
    float* s2 = s1 + 256;
    int*   si = (int*)(s2 + 256);
    if (hi == 0) {
        #pragma unroll
        for (int tt = 0; tt < 2; ++tt) {
            int tl = wn * 64 + tt * 32 + l31;
            s1[we * 128 + tl] = b1[tt];
            s2[we * 128 + tl] = b2[tt];
            si[we * 128 + tl] = bi[tt];
        }
    }
    __syncthreads();
    if (tid < TMTOK) {
        float v1 = s1[tid], v2 = s2[tid]; int vi = si[tid];
        float u1 = s1[128 + tid], u2 = s2[128 + tid];
        int   ui = si[128 + tid];
        if (u1 < v1 || (u1 == v1 && ui < vi)) { v2 = fminf(v1, u2); v1 = u1; vi = ui; }
        else                                  { v2 = fminf(v2, u1); }
        size_t o = (size_t)kb * Ntok + m0 + tid;
        pb1[o] = v1; pb2[o] = v2; pbi[o] = vi;
    }
}

// ---------------------------------------------------------------------------
// k2: combine splits per token; provisional global idx; flag near-ties.
__global__ __launch_bounds__(256)
void k2_combine(const float* __restrict__ pb1, const float* __restrict__ pb2,
                const int* __restrict__ pbi, const int* __restrict__ ridx,
                int* __restrict__ gidx, int* __restrict__ tlist,
                int* __restrict__ cnt, int Ntok, int nsplit) {
    int t = blockIdx.x * 256 + threadIdx.x;
    if (t >= Ntok) return;
    float v1 = INFINITY, v2 = INFINITY; int vi = 0x7fffffff;
    for (int kb = 0; kb < nsplit; ++kb) {
        size_t o = (size_t)kb * Ntok + t;
        float u1 = pb1[o], u2 = pb2[o]; int ui = pbi[o];
        if (u1 < v1 || (u1 == v1 && ui < vi)) { v2 = fminf(v1, u2); v1 = u1; vi = ui; }
        else                                  { v2 = fminf(v2, u1); }
    }
    gidx[t] = ridx[vi];
    if (v2 - v1 < TAU) {
        int pos = atomicAdd(cnt, 1);
        tlist[pos] = t;
    }
}

// ---------------------------------------------------------------------------
// k_recheck: exact f64 argmin, lexicographic tie-break, flagged tokens only.
__global__ __launch_bounds__(256)
void k_recheck(const float4* __restrict__ x4, const float4* __restrict__ cb4,
               const int* __restrict__ ridx, const int* __restrict__ tlist,
               const int* __restrict__ cnt, int* __restrict__ gidx, int K) {
    __shared__ float4 xls[D4];
    __shared__ double rv[256];
    __shared__ int    rix[256];
    const int tid = threadIdx.x;
    const int n   = *cnt;
    for (int fi = blockIdx.x; fi < n; fi += gridDim.x) {
        int t = tlist[fi];
        if (tid < D4) xls[tid] = x4[(size_t)t * D4 + tid];
        __syncthreads();
        double bv = INFINITY; int bi = 0x7fffffff;
        for (int k = tid; k < K; k += 256) {
            const float4* cr = cb4 + (size_t)ridx[k] * D4;
            double s = 0.0, cc = 0.0;
            #pragma unroll 4
            for (int d = 0; d < D4; ++d) {
                float4 cv = cr[d], xv = xls[d];
                s  = fma((double)cv.x, (double)xv.x, s);
                s  = fma((double)cv.y, (double)xv.y, s);
                s  = fma((double)cv.z, (double)xv.z, s);
                s  = fma((double)cv.w, (double)xv.w, s);
                cc = fma((double)cv.x, (double)cv.x, cc);
                cc = fma((double)cv.y, (double)cv.y, cc);
                cc = fma((double)cv.z, (double)cv.z, cc);
                cc = fma((double)cv.w, (double)cv.w, cc);
            }
            double sc = cc - 2.0 * s;
            if (sc < bv || (sc == bv && k < bi)) { bv = sc; bi = k; }
        }
        rv[tid] = bv; rix[tid] = bi;
        __syncthreads();
        for (int st = 128; st; st >>= 1) {
            if (tid < st) {
                double u = rv[tid + st]; int ui = rix[tid + st];
                if (u < rv[tid] || (u == rv[tid] && ui < rix[tid])) {
                    rv[tid] = u; rix[tid] = ui;
                }
            }
            __syncthreads();
        }
        if (tid == 0) gidx[t] = ridx[rix[0]];
        __syncthreads();
    }
}

// ---------------------------------------------------------------------------
// k3: gather codebook row per token, write tokens + float index + sq-err sum.
__global__ __launch_bounds__(256)
void k3_gather(const float4* __restrict__ x4, const float4* __restrict__ cb4,
               const int* __restrict__ gidx, float4* __restrict__ out_tok,
               float* __restrict__ out_idx, float* __restrict__ tok_loss,
               int Ntok) {
    int t    = (int)(blockIdx.x * 4 + (threadIdx.x >> 6));
    int lane = threadIdx.x & 63;
    if (t >= Ntok) return;
    int g = gidx[t];
    float4 cv = cb4[(size_t)g * D4 + lane];
    float4 xv = x4[(size_t)t * D4 + lane];
    out_tok[(size_t)t * D4 + lane] = cv;
    if (lane == 0) out_idx[t] = (float)g;
    float dx = cv.x - xv.x, dy = cv.y - xv.y, dz = cv.z - xv.z, dw = cv.w - xv.w;
    float s = dx * dx + dy * dy + dz * dz + dw * dw;
    #pragma unroll
    for (int off = 32; off; off >>= 1) s += __shfl_xor(s, off, 64);
    if (lane == 0) tok_loss[t] = s;
}

// ---------------------------------------------------------------------------
// k4: deterministic fixed-order loss mean (single block).
__global__ __launch_bounds__(256)
void k4_loss(const float* __restrict__ tok_loss, float* __restrict__ out_loss,
             int Ntok, double inv_total) {
    __shared__ double sm[256];
    double s = 0.0;
    for (int i = threadIdx.x; i < Ntok; i += 256) s += (double)tok_loss[i];
    sm[threadIdx.x] = s;
    __syncthreads();
    for (int st = 128; st; st >>= 1) {
        if ((int)threadIdx.x < st) sm[threadIdx.x] += sm[threadIdx.x + st];
        __syncthreads();
    }
    if (threadIdx.x == 0) *out_loss = (float)(sm[0] * inv_total);
}

// ---------------------------------------------------------------------------
// ---- f32 fallback path (round-2 proven) — only if ws too small ----
__global__ __launch_bounds__(256)
void k0_c2(const float4* __restrict__ cb4, const int* __restrict__ ridx,
           float* __restrict__ c2, int K, int kpad) {
    int k    = (int)(blockIdx.x * 4 + (threadIdx.x >> 6));
    int lane = threadIdx.x & 63;
    if (k >= kpad) return;
    double s = 0.0;
    if (k < K) {
        int row = ridx[k];
        float4 v = cb4[(size_t)row * D4 + lane];
        s = (double)v.x * v.x + (double)v.y * v.y
          + (double)v.z * v.z + (double)v.w * v.w;
    }
    #pragma unroll
    for (int off = 32; off; off >>= 1) s += __shfl_xor(s, off, 64);
    if (lane == 0) c2[k] = (k < K) ? (float)s : INFINITY;
}

__global__ __launch_bounds__(256, 2)
void fk1_argmin(const float4* __restrict__ x4, const float4* __restrict__ cb4,
                const int* __restrict__ ridx, const float* __restrict__ c2,
                float* __restrict__ pb1, float* __restrict__ pb2,
                int* __restrict__ pbi, int Ntok, int K, int kspan) {
    __shared__ float4 xs4[128 * 16];
    __shared__ float4 cs4[128 * 16];
    __shared__ float  c2_t[128];
    const int tid = threadIdx.x;
    const int r = tid >> 4, c = tid & 15;
    const int m0 = blockIdx.x * 128;
    const int kbase0 = blockIdx.y * kspan;
    float b1[8], b2[8]; int bi[8];
    #pragma unroll
    for (int i = 0; i < 8; ++i) { b1[i] = INFINITY; b2[i] = INFINITY; bi[i] = 0; }
    for (int t = 0; t < 8; ++t) {
        const int kbase = kbase0 + t * 128;
        if (kbase >= K) break;
        __syncthreads();
        if (tid < 128) c2_t[tid] = c2[kbase + tid];
        int cidx[8];
        #pragma unroll
        for (int q = 0; q < 8; ++q) {
            int k = kbase + 16 * q + r;
            cidx[q] = ridx[(k < K) ? k : 0];
        }
        float acc[8][8];
        #pragma unroll
        for (int i = 0; i < 8; ++i)
            #pragma unroll
            for (int j = 0; j < 8; ++j) acc[i][j] = 0.f;
        for (int ch = 0; ch < 4; ++ch) {
            __syncthreads();
            #pragma unroll
            for (int q = 0; q < 8; ++q) {
                int row = 16 * q + r;
                int p   = c ^ (row & 7);
                xs4[row * 16 + p] = x4[(size_t)(m0 + row) * D4 + ch * 16 + c];
                cs4[row * 16 + p] = cb4[(size_t)cidx[q] * D4 + ch * 16 + c];
            }
            __syncthreads();
            #pragma unroll 2
            for (int f = 0; f < 16; ++f) {
                float4 xf[8];
                #pragma unroll
                for (int i = 0; i < 8; ++i) xf[i] = xs4[(8 * r + i) * 16 + (f ^ i)];
                #pragma unroll
                for (int j = 0; j < 8; ++j) {
                    float4 cf = cs4[(c + 16 * j) * 16 + (f ^ (c & 7))];
                    #pragma unroll
                    for (int i = 0; i < 8; ++i) {
                        acc[i][j] = fmaf(xf[i].x, cf.x, acc[i][j]);
                        acc[i][j] = fmaf(xf[i].y, cf.y, acc[i][j]);
                        acc[i][j] = fmaf(xf[i].z, cf.z, acc[i][j]);
                        acc[i][j] = fmaf(xf[i].w, cf.w, acc[i][j]);
                    }
                }
            }
        }
        #pragma unroll
        for (int j = 0; j < 8; ++j) {
            float c2v = c2_t[c + 16 * j];
            int   k   = kbase + c + 16 * j;
            #pragma unroll
            for (int i = 0; i < 8; ++i) {
                float sc = fmaf(-2.f, acc[i][j], c2v);
                if (sc < b1[i]) { b2[i] = b1[i]; b1[i] = sc; bi[i] = k; }
                else            { b2[i] = fminf(b2[i], sc); }
            }
        }
    }
    __syncthreads();
    float* s1 = (float*)xs4;
    float* s2 = s1 + 128 * 16;
    int*   si = (int*)cs4;
    #pragma unroll
    for (int i = 0; i < 8; ++i) {
        int row = 8 * r + i;
        s1[row * 16 + c] = b1[i]; s2[row * 16 + c] = b2[i]; si[row * 16 + c] = bi[i];
    }
    __syncthreads();
    if (tid < 128) {
        float v1 = s1[tid * 16], v2 = s2[tid * 16];
        int   vi = si[tid * 16];
        #pragma unroll
        for (int cc = 1; cc < 16; ++cc) {
            float u1 = s1[tid * 16 + cc], u2 = s2[tid * 16 + cc];
            int   ui = si[tid * 16 + cc];
            if (u1 < v1 || (u1 == v1 && ui < vi)) { v2 = fminf(v1, u2); v1 = u1; vi = ui; }
            else                                  { v2 = fminf(v2, u1); }
        }
        size_t o = (size_t)blockIdx.y * Ntok + m0 + tid;
        pb1[o] = v1; pb2[o] = v2; pbi[o] = vi;
    }
}

// ---------------------------------------------------------------------------
extern "C" void kernel_launch(void* const* d_in, const int* in_sizes, int n_in,
                              void* d_out, int out_size, void* d_ws, size_t ws_size,
                              hipStream_t stream) {
    const float* x    = (const float*)d_in[0];
    const float* cb   = (const float*)d_in[1];
    const int*   ridx = (const int*)d_in[2];

    const int Ntok = in_sizes[0] / D;          // 16384
    const int K    = in_sizes[2];              // 3686

    float* out      = (float*)d_out;
    float* out_loss = out + (size_t)Ntok * D;
    float* out_idx  = out + (size_t)Ntok * D + 1;

    const float4* x4  = (const float4*)x;
    const float4* cb4 = (const float4*)cb;

    auto up = [](size_t v) { return (v + 255) & ~(size_t)255; };

    size_t need = 256 + up((size_t)KPAD * 512 * 2) + up((size_t)KPAD * 4)
                + 3 * up((size_t)NSPLIT * Ntok * 4) + 3 * up((size_t)Ntok * 4);

    const int gblocks = (Ntok + 3) / 4;
    const double inv_total = 1.0 / ((double)Ntok * (double)D);

    if (ws_size >= need && (Ntok & 127) == 0) {
        // ---------------- MFMA pipeline path ----------------
        char* w = (char*)d_ws;
        int*    cnt   = (int*)w;    w += 256;
        ushort* cpF   = (ushort*)w; w += up((size_t)KPAD * 512 * 2);
        float*  c2    = (float*)w;  w += up((size_t)KPAD * 4);
        float*  pb1   = (float*)w;  w += up((size_t)NSPLIT * Ntok * 4);
        float*  pb2   = (float*)w;  w += up((size_t)NSPLIT * Ntok * 4);
        int*    pbi   = (int*)w;    w += up((size_t)NSPLIT * Ntok * 4);
        int*    gidx  = (int*)w;    w += up((size_t)Ntok * 4);
        int*    tlist = (int*)w;    w += up((size_t)Ntok * 4);
        float*  tl    = (float*)w;

        ushort* xpF = (ushort*)d_out;   // 16.8 MB: exact fit in out_tok region

        const int nwav = 16 * (Ntok >> 5) + 16 * NEB + KPAD;

        hipMemsetAsync(cnt, 0, 4, stream);
        p01_pack<<<dim3((nwav + 3) / 4), dim3(256), 0, stream>>>(
            x4, cb4, ridx, xpF, cpF, c2, Ntok, K);
        k1_mfma<<<dim3((Ntok / TMTOK) * NSPLIT), dim3(256), 0, stream>>>(
            xpF, cpF, c2, pb1, pb2, pbi, Ntok);
        k2_combine<<<dim3((Ntok + 255) / 256), dim3(256), 0, stream>>>(
            pb1, pb2, pbi, ridx, gidx, tlist, cnt, Ntok, NSPLIT);
        k_recheck<<<dim3(256), dim3(256), 0, stream>>>(
            x4, cb4, ridx, tlist, cnt, gidx, K);
        k3_gather<<<dim3(gblocks), dim3(256), 0, stream>>>(
            x4, cb4, gidx, (float4*)out, out_idx, tl, Ntok);
        k4_loss<<<dim3(1), dim3(256), 0, stream>>>(tl, out_loss, Ntok, inv_total);
    } else {
        // ---------------- f32 fallback (round-2 proven) ----------------
        const int kpad  = 4096;
        const int kspan = 1024;
        char* w = (char*)d_ws;
        int*   cnt   = (int*)w;    w += 256;
        float* c2    = (float*)w;  w += up((size_t)kpad * 4);
        float* pb1   = (float*)w;  w += up((size_t)4 * Ntok * 4);
        float* pb2   = (float*)w;  w += up((size_t)4 * Ntok * 4);
        int*   pbi   = (int*)w;    w += up((size_t)4 * Ntok * 4);
        int*   gidx  = (int*)w;    w += up((size_t)Ntok * 4);
        int*   tlist = (int*)w;    w += up((size_t)Ntok * 4);
        float* tl    = (float*)w;

        hipMemsetAsync(cnt, 0, 4, stream);
        k0_c2<<<dim3(kpad / 4), dim3(256), 0, stream>>>(cb4, ridx, c2, K, kpad);
        fk1_argmin<<<dim3(Ntok / 128, 4), dim3(256), 0, stream>>>(
            x4, cb4, ridx, c2, pb1, pb2, pbi, Ntok, K, kspan);
        k2_combine<<<dim3((Ntok + 255) / 256), dim3(256), 0, stream>>>(
            pb1, pb2, pbi, ridx, gidx, tlist, cnt, Ntok, 4);
        k_recheck<<<dim3(256), dim3(256), 0, stream>>>(
            x4, cb4, ridx, tlist, cnt, gidx, K);
        k3_gather<<<dim3(gblocks), dim3(256), 0, stream>>>(
            x4, cb4, gidx, (float4*)out, out_idx, tl, Ntok);
        k4_loss<<<dim3(1), dim3(256), 0, stream>>>(tl, out_loss, Ntok, inv_total);
    }
}